// Round 5
// baseline (326.911 us; speedup 1.0000x reference)
//
#include <hip/hip_runtime.h>

typedef __attribute__((ext_vector_type(8))) short bf16x8;
typedef __attribute__((ext_vector_type(4))) float f32x4;

#define C1N 1024
#define CP 256
#define C2N 32
#define NPB 1024
#define BATCH 8
#define BK 64

__device__ __forceinline__ unsigned short f2bf(float f) {
  unsigned u = __float_as_uint(f);
  u += 0x7fffu + ((u >> 16) & 1u);   // RNE round to bf16
  return (unsigned short)(u >> 16);
}

// ---------------- Kernel P: xn = LayerNorm_c(x) (layout [b][c][n])
//                  + convert Wp f32 -> bf16 ----------------
__global__ __launch_bounds__(256) void prep_kernel(
    const float* __restrict__ x, const float* __restrict__ Wp,
    const float* __restrict__ g2, const float* __restrict__ b2,
    short* __restrict__ Wpb, float* __restrict__ xn)
{
  const int tid = threadIdx.x;
  if (blockIdx.x < 32) {
    // LayerNorm over C2=32 channels for each (b, n)
    int g = blockIdx.x * 256 + tid;           // 0..8191 = B*N
    int b = g >> 10, n = g & 1023;
    const float* xb = x + (size_t)b * C2N * NPB + n;
    float v[C2N];
    float s = 0.f;
#pragma unroll
    for (int c = 0; c < C2N; ++c) { v[c] = xb[(size_t)c * NPB]; s += v[c]; }
    float m = s * (1.0f / C2N);
    float s2 = 0.f;
#pragma unroll
    for (int c = 0; c < C2N; ++c) { float d = v[c] - m; s2 += d * d; }
    float rs = rsqrtf(s2 * (1.0f / C2N) + 1e-5f);
    float* xo = xn + (size_t)b * C2N * NPB + n;
#pragma unroll
    for (int c = 0; c < C2N; ++c) xo[(size_t)c * NPB] = (v[c] - m) * rs * g2[c] + b2[c];
  } else {
    // Wp f32 [256][1024] -> bf16
    int base = (blockIdx.x - 32) * 256 + tid;  // 0..8191
#pragma unroll
    for (int it = 0; it < 8; ++it) {
      int pos = it * 8192 + base;              // float4 index, 65536 total
      f32x4 w = ((const f32x4*)Wp)[pos];
      ushort4 o;
      o.x = f2bf(w.x); o.y = f2bf(w.y); o.z = f2bf(w.z); o.w = f2bf(w.w);
      ((ushort4*)Wpb)[pos] = o;
    }
  }
}

// ---------------- Kernel B: proj_t[b] = Wp_bf16 @ q[b]  (MFMA),
//   then LayerNorm over d (Cp=256) per column n, write qn_t [b][d][n] ----------------
__global__ __launch_bounds__(256) void gemm_ln_kernel(
    const float* __restrict__ q, const short* __restrict__ Wpb,
    const float* __restrict__ bp, const float* __restrict__ g1, const float* __restrict__ b1,
    float* __restrict__ qn)
{
  __shared__ short Wp_s[2][CP * BK];           // 2 x 32 KB, XOR-swizzled k-slots
  __shared__ float p1[4][32], p2[4][32], lm[32], lr[32];

  const int tid  = threadIdx.x;
  const int lane = tid & 63;
  const int wv   = tid >> 6;                   // wave 0..3 -> d rows [64w, 64w+64)
  const int colA = lane & 15;
  const int grp  = lane >> 4;                  // 0..3 (k-group)
  const int bb   = blockIdx.y;
  const int n0   = blockIdx.x * 32;

  const float* qb = q + (size_t)bb * C1N * NPB;

  f32x4 acc[4][2];
#pragma unroll
  for (int i = 0; i < 4; ++i)
#pragma unroll
    for (int j = 0; j < 2; ++j) acc[i][j] = (f32x4){0.f, 0.f, 0.f, 0.f};

  const int drow_off = lane >> 3;              // 0..7
  const int kslot_g  = (lane & 7) ^ drow_off;  // pre-swizzled global k-slot

  // stage Wp tile [256][BK] for K-step ks into buf (linear LDS dest, swizzled global src)
  auto stage = [&](int buf, int ks) {
    const int k0 = ks * BK;
#pragma unroll
    for (int i = 0; i < 8; ++i) {
      int d0 = wv * 64 + i * 8;                // wave-uniform
      const short* gsrc = Wpb + (size_t)(d0 + drow_off) * C1N + k0 + kslot_g * 8;
      short* ldst = &Wp_s[buf][d0 * BK];
      __builtin_amdgcn_global_load_lds((const __attribute__((address_space(1))) void*)gsrc,
                                       (__attribute__((address_space(3))) void*)ldst,
                                       16, 0, 0);
    }
  };

  stage(0, 0);
  __syncthreads();

  for (int ks = 0; ks < C1N / BK; ++ks) {
    const int cur = ks & 1;
    if (ks < C1N / BK - 1) stage(cur ^ 1, ks + 1);

    const float* qk = qb + (size_t)(ks * BK) * NPB + n0;
#pragma unroll
    for (int kk2 = 0; kk2 < 2; ++kk2) {        // two K=32 MFMA steps per BK=64
      bf16x8 bfrag[2];
#pragma unroll
      for (int nf = 0; nf < 2; ++nf) {
#pragma unroll
        for (int j = 0; j < 8; ++j) {
          float v = qk[(size_t)(kk2 * 32 + grp * 8 + j) * NPB + nf * 16 + colA];
          bfrag[nf][j] = (short)f2bf(v);
        }
      }
#pragma unroll
      for (int df = 0; df < 4; ++df) {
        int row  = wv * 64 + df * 16 + colA;
        int boff = row * (BK * 2) + ((((kk2 << 2) + grp) ^ (row & 7)) << 4);
        bf16x8 afrag = *(const bf16x8*)((const char*)&Wp_s[cur][0] + boff);
        acc[df][0] = __builtin_amdgcn_mfma_f32_16x16x32_bf16(afrag, bfrag[0], acc[df][0], 0, 0, 0);
        acc[df][1] = __builtin_amdgcn_mfma_f32_16x16x32_bf16(afrag, bfrag[1], acc[df][1], 0, 0, 0);
      }
    }
    __syncthreads();
  }

  // ---- epilogue: +bp, LayerNorm over d (256), write qn_t ----
  float s1[2] = {0.f, 0.f}, s2[2] = {0.f, 0.f};
#pragma unroll
  for (int df = 0; df < 4; ++df) {
#pragma unroll
    for (int r = 0; r < 4; ++r) {
      int d = wv * 64 + df * 16 + grp * 4 + r;
      float bpv = bp[d];
#pragma unroll
      for (int nf = 0; nf < 2; ++nf) {
        acc[df][nf][r] += bpv;
        float v = acc[df][nf][r];
        s1[nf] += v; s2[nf] += v * v;
      }
    }
  }
#pragma unroll
  for (int nf = 0; nf < 2; ++nf) {
    s1[nf] += __shfl_xor(s1[nf], 16); s1[nf] += __shfl_xor(s1[nf], 32);
    s2[nf] += __shfl_xor(s2[nf], 16); s2[nf] += __shfl_xor(s2[nf], 32);
  }
  if (lane < 16) {
    p1[wv][lane] = s1[0]; p1[wv][16 + lane] = s1[1];
    p2[wv][lane] = s2[0]; p2[wv][16 + lane] = s2[1];
  }
  __syncthreads();
  if (tid < 32) {
    float a1 = p1[0][tid] + p1[1][tid] + p1[2][tid] + p1[3][tid];
    float a2 = p2[0][tid] + p2[1][tid] + p2[2][tid] + p2[3][tid];
    float m  = a1 * (1.0f / CP);
    float var = a2 * (1.0f / CP) - m * m;
    lm[tid] = m;
    lr[tid] = rsqrtf(var + 1e-5f);
  }
  __syncthreads();
#pragma unroll
  for (int df = 0; df < 4; ++df) {
#pragma unroll
    for (int r = 0; r < 4; ++r) {
      int d = wv * 64 + df * 16 + grp * 4 + r;
      float gv = g1[d], bv = b1[d];
#pragma unroll
      for (int nf = 0; nf < 2; ++nf) {
        int col = nf * 16 + colA;
        float outv = (acc[df][nf][r] - lm[col]) * lr[col] * gv + bv;
        qn[((size_t)bb * CP + d) * NPB + n0 + col] = outv;
      }
    }
  }
}

// ---------------- Kernel C: out[b][d*32+c][n] = qn_t[b][d][n] * xn[b][c][n] ----------------
__global__ __launch_bounds__(256) void outer_kernel(
    const float* __restrict__ qn, const float* __restrict__ xn, float* __restrict__ out)
{
  const int blk = blockIdx.x;                  // 0..2047
  const int bb = blk >> 8;
  const int d  = blk & 255;
  const int n4 = threadIdx.x * 4;

  const f32x4 qv = *(const f32x4*)(qn + ((size_t)bb * CP + d) * NPB + n4);
  const float* xb = xn + (size_t)bb * C2N * NPB + n4;
  float* ob = out + ((size_t)bb * (CP * C2N) + (size_t)d * C2N) * NPB + n4;

#pragma unroll 8
  for (int c = 0; c < C2N; ++c) {
    f32x4 xv = *(const f32x4*)(xb + (size_t)c * NPB);
    f32x4 ov = qv * xv;
    __builtin_nontemporal_store(ov, (f32x4*)(ob + (size_t)c * NPB));
  }
}

extern "C" void kernel_launch(void* const* d_in, const int* in_sizes, int n_in,
                              void* d_out, int out_size, void* d_ws, size_t ws_size,
                              hipStream_t stream) {
  const float* q  = (const float*)d_in[0];
  const float* x  = (const float*)d_in[1];
  const float* Wp = (const float*)d_in[2];
  const float* bp = (const float*)d_in[3];
  const float* g1 = (const float*)d_in[4];
  const float* b1 = (const float*)d_in[5];
  const float* g2 = (const float*)d_in[6];
  const float* b2 = (const float*)d_in[7];
  float* out = (float*)d_out;

  // workspace layout: Wpb bf16 (512 KB) | xn f32 (1 MB) | qn_t f32 (8 MB)
  short* Wpb = (short*)d_ws;
  float* xn  = (float*)((char*)d_ws + (512 << 10));
  float* qn  = (float*)((char*)d_ws + (512 << 10) + (1 << 20));

  prep_kernel<<<64, 256, 0, stream>>>(x, Wp, g2, b2, Wpb, xn);
  gemm_ln_kernel<<<dim3(32, 8), 256, 0, stream>>>(q, Wpb, bp, g1, b1, qn);
  outer_kernel<<<2048, 256, 0, stream>>>(qn, xn, out);
}